// Round 13
// baseline (198.749 us; speedup 1.0000x reference)
//
#include <hip/hip_runtime.h>
#include <stdint.h>

// ---------------------------------------------------------------------------
// SNN EMNIST forward: T=10, B=4096, IN=784, HID=256, NCLS=47
// splitk (EXACT 3-way bf16 W1) -> fused spikegen+MFMA gemm -> fused scan+out.
// R13 = R12 structure with the threefry hash as ONE 72-instruction inline-asm
// block per hash (R7/R8 failed with per-ROUND asm = 20 boundaries/hash of
// mov storms; a single block has 1 boundary and hand-minimal codegen:
// measured ~160 VALU-ops/hash vs ~80 ideal). Element offset j is baked into
// the first instruction (x1 = ib + (42+j), inline consts 42..49).
// Integer ops only -> output bitwise-identical to R12 (absmax 4.882812e-4).
// ---------------------------------------------------------------------------

#define T_STEPS 10
#define BATCH   4096
#define IN_DIM  784
#define HID     256
#define NCLS    47
#define NROWS   (T_STEPS * BATCH)        // 40960
#define KWORDS  25                       // ceil(784/32)
#define KPAD    800                      // 25*32

// d_ws layout (bytes):
//   [0, 41943040)          I_all  : float [40960][256]
//   [46039040, ...)        W1{hi,mid,lo}T : bf16 [256][800], 409600 B each
#define WS_IALL_OFF 0u
#define WS_W1HI_OFF 46039040u
#define WS_W1MD_OFF (46039040u + 409600u)
#define WS_W1LO_OFF (46039040u + 819200u)

typedef __attribute__((ext_vector_type(8))) short    bf16x8;
typedef __attribute__((ext_vector_type(4))) float    f32x4;
typedef __attribute__((ext_vector_type(4))) uint32_t u32x4;

// ---------------------------------------------------------------------------
// Threefry2x32, key=(0,42), partitionable: counter=(0, lo), out=(o0^o1)>>9.
// ks0=0, ks1=42, ks2=0x1BD11BDA^42=0x1BD11BF0. Rotations per 4-round group:
// {13,15,26,6} / {17,29,16,24} -> alignbit shifts {19,17,6,26} / {15,3,16,8}.
// One asm block = whole hash: init(1) + R1(3,incl mov) + 19x3 + inj(9) +
// final xor+shr(2) = 72 instrs. J42 = "42".."49" bakes element offset j.
// ---------------------------------------------------------------------------
#define TF_G1(x0, x1) \
    "v_add_u32 " x0 ", " x0 ", " x1 "\n\t" \
    "v_alignbit_b32 " x1 ", " x1 ", " x1 ", 19\n\t" \
    "v_xor_b32 " x1 ", " x1 ", " x0 "\n\t" \
    "v_add_u32 " x0 ", " x0 ", " x1 "\n\t" \
    "v_alignbit_b32 " x1 ", " x1 ", " x1 ", 17\n\t" \
    "v_xor_b32 " x1 ", " x1 ", " x0 "\n\t" \
    "v_add_u32 " x0 ", " x0 ", " x1 "\n\t" \
    "v_alignbit_b32 " x1 ", " x1 ", " x1 ", 6\n\t" \
    "v_xor_b32 " x1 ", " x1 ", " x0 "\n\t" \
    "v_add_u32 " x0 ", " x0 ", " x1 "\n\t" \
    "v_alignbit_b32 " x1 ", " x1 ", " x1 ", 26\n\t" \
    "v_xor_b32 " x1 ", " x1 ", " x0 "\n\t"

#define TF_G2(x0, x1) \
    "v_add_u32 " x0 ", " x0 ", " x1 "\n\t" \
    "v_alignbit_b32 " x1 ", " x1 ", " x1 ", 15\n\t" \
    "v_xor_b32 " x1 ", " x1 ", " x0 "\n\t" \
    "v_add_u32 " x0 ", " x0 ", " x1 "\n\t" \
    "v_alignbit_b32 " x1 ", " x1 ", " x1 ", 3\n\t" \
    "v_xor_b32 " x1 ", " x1 ", " x0 "\n\t" \
    "v_add_u32 " x0 ", " x0 ", " x1 "\n\t" \
    "v_alignbit_b32 " x1 ", " x1 ", " x1 ", 16\n\t" \
    "v_xor_b32 " x1 ", " x1 ", " x0 "\n\t" \
    "v_add_u32 " x0 ", " x0 ", " x1 "\n\t" \
    "v_alignbit_b32 " x1 ", " x1 ", " x1 ", 8\n\t" \
    "v_xor_b32 " x1 ", " x1 ", " x0 "\n\t"

// m = threefry(0, ib+j) folded and >>9.  J42 = string of (42+j).
#define TF_HASH9(m, ib, J42) do {                                   \
    uint32_t _x0, _x1;                                              \
    asm("v_add_u32 %1, " J42 ", %2\n\t"       /* x1 = ib + 42+j */  \
        "v_mov_b32 %0, %1\n\t"                /* R1: x0 += x1   */  \
        "v_alignbit_b32 %1, %1, %1, 19\n\t"                         \
        "v_xor_b32 %1, %1, %0\n\t"                                  \
        "v_add_u32 %0, %0, %1\n\t"            /* R2 */              \
        "v_alignbit_b32 %1, %1, %1, 17\n\t"                         \
        "v_xor_b32 %1, %1, %0\n\t"                                  \
        "v_add_u32 %0, %0, %1\n\t"            /* R3 */              \
        "v_alignbit_b32 %1, %1, %1, 6\n\t"                          \
        "v_xor_b32 %1, %1, %0\n\t"                                  \
        "v_add_u32 %0, %0, %1\n\t"            /* R4 */              \
        "v_alignbit_b32 %1, %1, %1, 26\n\t"                         \
        "v_xor_b32 %1, %1, %0\n\t"                                  \
        "v_add_u32 %0, 42, %0\n\t"            /* x0 += ks1 */       \
        "v_add_u32 %1, 0x1bd11bf1, %1\n\t"    /* x1 += ks2+1 */     \
        TF_G2("%0", "%1")                     /* R5-R8 */           \
        "v_add_u32 %0, 0x1bd11bf0, %0\n\t"    /* x0 += ks2 */       \
        "v_add_u32 %1, 2, %1\n\t"             /* x1 += ks0+2 */     \
        TF_G1("%0", "%1")                     /* R9-R12 */          \
        "v_add_u32 %1, 45, %1\n\t"            /* x1 += ks1+3 */     \
        TF_G2("%0", "%1")                     /* R13-R16 */         \
        "v_add_u32 %0, 42, %0\n\t"            /* x0 += ks1 */       \
        "v_add_u32 %1, 0x1bd11bf4, %1\n\t"    /* x1 += ks2+4 */     \
        TF_G1("%0", "%1")                     /* R17-R20 */         \
        "v_add_u32 %0, 0x1bd11bf0, %0\n\t"    /* x0 += ks2 */       \
        "v_add_u32 %1, 5, %1\n\t"             /* x1 += ks0+5 */     \
        "v_xor_b32 %0, %0, %1\n\t"            /* o0^o1 */           \
        "v_lshrrev_b32 %0, 9, %0"             /* >>9 */             \
        : "=&v"(_x0), "=&v"(_x1) : "v"(ib));                        \
    m = _x0;                                                        \
} while (0)

// ---------------------------------------------------------------------------
// Kernel B0: split W1 (f32 [784][256]) into transposed bf16 hi/mid/lo
// [256][800]. EXACT: hi+mid+lo == w bitwise.
// ---------------------------------------------------------------------------
__global__ __launch_bounds__(256) void splitk_k(
        const float* __restrict__ W1, ushort* __restrict__ hiT,
        ushort* __restrict__ midT, ushort* __restrict__ loT) {
    int n = blockIdx.x;                  // 0..255
    for (int k = threadIdx.x; k < KPAD; k += 256) {
        float w = (k < IN_DIM) ? W1[k * HID + n] : 0.0f;
        uint32_t u = __float_as_uint(w);
        uint32_t hb = (u + 0x7FFFu + ((u >> 16) & 1u)) >> 16;    // RNE to bf16
        float hf = __uint_as_float(hb << 16);
        float r1 = w - hf;                                       // exact
        uint32_t u1 = __float_as_uint(r1);
        uint32_t mb = (u1 + 0x7FFFu + ((u1 >> 16) & 1u)) >> 16;  // RNE
        float mf2 = __uint_as_float(mb << 16);
        float r2 = r1 - mf2;                                     // exact
        uint32_t u2 = __float_as_uint(r2);
        uint32_t lb = (u2 + 0x7FFFu + ((u2 >> 16) & 1u)) >> 16;  // exact fit
        hiT [n * KPAD + k] = (ushort)hb;
        midT[n * KPAD + k] = (ushort)mb;
        loT [n * KPAD + k] = (ushort)lb;
    }
}

// ---------------------------------------------------------------------------
// Fused spikegen + GEMM: I_all = bernoulli(x) @ W1 + b1.
// Block: 64 rows (one t, 64 b) x 256 cols, 4 waves; wave = 64x64 = 4x4 tiles
// of 16x16x32. K-loop over 25 slabs, canonical order. Per iter: [sync] ->
// issue B[kw] global_load_lds (hoisted pointers, +32 elem/iter) -> hash this
// slab's 8 spike bits/thread (single-asm-block threefry) -> ds_write A frag
// -> [sync] -> 48 MFMA. XOR-swizzled 16B quarters keep ds_read_b128 <=2-way.
// Accum order identical to R4/R6/R8/R12 -> bitwise-identical I_all.
// ---------------------------------------------------------------------------
#define LDS_A  0
#define LDS_BH 4096
#define LDS_BM 20480
#define LDS_BL 36864

__global__ __launch_bounds__(256, 3) void fused_gemm_k(
        const ushort* __restrict__ hiT, const ushort* __restrict__ midT,
        const ushort* __restrict__ loT, const float* __restrict__ b1,
        const float* __restrict__ x, float* __restrict__ I_all) {
    __shared__ __align__(16) char lds[53248];

    const int tid = threadIdx.x;
    const int l   = tid & 63;
    const int wv  = tid >> 6;
    const int t   = blockIdx.x >> 6;     // 64 blocks per timestep
    const int b0  = (blockIdx.x & 63) << 6;
    const int m0  = blockIdx.x << 6;

    f32x4 acc[4][4] = {};

    // fragment read addressing (shared swizzle sig for A and B)
    const int q   = l >> 4;
    const int sig = q ^ (l & 3) ^ ((l >> 2) & 3);
    const int a_base = LDS_A + ((l & 15) << 6) + (sig << 4);
    const int b_off  = (((wv << 6) + (l & 15)) << 6) + (sig << 4);

    // ---- loop-invariant staging addresses ----
    const ushort* hi_p[4];
    const ushort* md_p[4];
    const ushort* lo_p[4];
    int ldst_c[4];
#pragma unroll
    for (int i = 0; i < 4; ++i) {
        int s  = (wv << 8) + (i << 6) + l;
        int n  = s >> 2;
        int qs = s & 3;
        int qd = qs ^ (n & 3) ^ ((n >> 2) & 3);
        size_t eoff = (size_t)n * KPAD + ((size_t)qd << 3);
        hi_p[i] = hiT  + eoff;
        md_p[i] = midT + eoff;
        lo_p[i] = loT  + eoff;
        ldst_c[i] = ((wv << 8) + (i << 6)) << 4;
    }

    // A-expansion thread mapping: row er (0..63), byte-group eq (0..3)
    const int er = tid >> 2;
    const int eq = tid & 3;
    const int ea = LDS_A + (er << 6) + ((eq ^ (er & 3) ^ ((er >> 2) & 3)) << 4);
    const int row_b = b0 + er;
    const float* xp = x + (size_t)row_b * IN_DIM + (eq << 3);   // +32/iter
    uint32_t ib = (uint32_t)(row_b * IN_DIM) + (uint32_t)(eq << 3)
                + (uint32_t)t * (uint32_t)(BATCH * IN_DIM);     // +32/iter

    for (int kw = 0; kw < KWORDS; ++kw) {
        __syncthreads();   // previous compute done with LDS

        // --- stage Bhi/Bmid/Blo K-slab (hoisted pointers) ---
#pragma unroll
        for (int i = 0; i < 4; ++i) {
            __builtin_amdgcn_global_load_lds(
                (const __attribute__((address_space(1))) void*)hi_p[i],
                (__attribute__((address_space(3))) void*)(lds + LDS_BH + ldst_c[i]),
                16, 0, 0);
            __builtin_amdgcn_global_load_lds(
                (const __attribute__((address_space(1))) void*)md_p[i],
                (__attribute__((address_space(3))) void*)(lds + LDS_BM + ldst_c[i]),
                16, 0, 0);
            __builtin_amdgcn_global_load_lds(
                (const __attribute__((address_space(1))) void*)lo_p[i],
                (__attribute__((address_space(3))) void*)(lds + LDS_BL + ldst_c[i]),
                16, 0, 0);
            hi_p[i] += 32;  md_p[i] += 32;  lo_p[i] += 32;
        }

        // --- inline spikegen: 8 single-block asm hashes -> A frag (16 B) ---
        {
            u32x4 v = {0u, 0u, 0u, 0u};
            // kw==24: k>=784 doesn't exist for eq>=2 -> keep zeros (also
            // guards the x OOB read on the last batch row).
            if (!(kw == 24 && eq >= 2)) {
                float4 xa = *(const float4*)xp;
                float4 xb = *(const float4*)(xp + 4);
                uint32_t m0h, m1h, m2h, m3h, m4h, m5h, m6h, m7h;
                TF_HASH9(m0h, ib, "42");
                TF_HASH9(m1h, ib, "43");
                TF_HASH9(m2h, ib, "44");
                TF_HASH9(m3h, ib, "45");
                TF_HASH9(m4h, ib, "46");
                TF_HASH9(m5h, ib, "47");
                TF_HASH9(m6h, ib, "48");
                TF_HASH9(m7h, ib, "49");
                uint32_t c0 = ((float)m0h < xa.x * 8388608.0f) ? 0x3F80u : 0u;
                uint32_t c1 = ((float)m1h < xa.y * 8388608.0f) ? 0x3F800000u : 0u;
                uint32_t c2 = ((float)m2h < xa.z * 8388608.0f) ? 0x3F80u : 0u;
                uint32_t c3 = ((float)m3h < xa.w * 8388608.0f) ? 0x3F800000u : 0u;
                uint32_t c4 = ((float)m4h < xb.x * 8388608.0f) ? 0x3F80u : 0u;
                uint32_t c5 = ((float)m5h < xb.y * 8388608.0f) ? 0x3F800000u : 0u;
                uint32_t c6 = ((float)m6h < xb.z * 8388608.0f) ? 0x3F80u : 0u;
                uint32_t c7 = ((float)m7h < xb.w * 8388608.0f) ? 0x3F800000u : 0u;
                v.x = c0 | c1;  v.y = c2 | c3;  v.z = c4 | c5;  v.w = c6 | c7;
            }
            *(u32x4*)(lds + ea) = v;     // always store (zeros on tail)
        }
        xp += 32;  ib += 32u;

        __syncthreads();   // A visible + global_load_lds drained

        // --- compute: 4 mtiles x 4 ntiles x (hi,mid,lo) = 48 MFMA ---
        bf16x8 af[4];
#pragma unroll
        for (int mt = 0; mt < 4; ++mt)
            af[mt] = *(const bf16x8*)(lds + a_base + (mt << 10));
#pragma unroll
        for (int nt = 0; nt < 4; ++nt) {
            bf16x8 bh = *(const bf16x8*)(lds + LDS_BH + b_off + (nt << 10));
            bf16x8 bm = *(const bf16x8*)(lds + LDS_BM + b_off + (nt << 10));
            bf16x8 bl = *(const bf16x8*)(lds + LDS_BL + b_off + (nt << 10));
#pragma unroll
            for (int mt = 0; mt < 4; ++mt) {
                acc[mt][nt] = __builtin_amdgcn_mfma_f32_16x16x32_bf16(af[mt], bh, acc[mt][nt], 0, 0, 0);
                acc[mt][nt] = __builtin_amdgcn_mfma_f32_16x16x32_bf16(af[mt], bm, acc[mt][nt], 0, 0, 0);
                acc[mt][nt] = __builtin_amdgcn_mfma_f32_16x16x32_bf16(af[mt], bl, acc[mt][nt], 0, 0, 0);
            }
        }
    }

    // --- epilogue: acc -> I_all (+ b1) ---
    const int c0 = l & 15;
    float b1v[4];
#pragma unroll
    for (int nt = 0; nt < 4; ++nt)
        b1v[nt] = b1[(wv << 6) + (nt << 4) + c0];
#pragma unroll
    for (int mt = 0; mt < 4; ++mt) {
#pragma unroll
        for (int nt = 0; nt < 4; ++nt) {
            int col = (wv << 6) + (nt << 4) + c0;
#pragma unroll
            for (int r = 0; r < 4; ++r) {
                int row = m0 + (mt << 4) + (q << 2) + r;
                I_all[(size_t)row * HID + col] = acc[mt][nt][r] + b1v[nt];
            }
        }
    }
}

// ---------------------------------------------------------------------------
// Fused LIF scan + readout: per block, 16 batch rows.
// ---------------------------------------------------------------------------
__global__ __launch_bounds__(256) void scanout_k(
        const float* __restrict__ I_all, const float* __restrict__ Wr,
        const float* __restrict__ br, float* __restrict__ out) {
    __shared__ float gl[16 * 256];       // 16 KB
    const int tid = threadIdx.x;
    const int b0  = blockIdx.x << 4;

#pragma unroll 4
    for (int b = 0; b < 16; ++b) {
        const float* p = I_all + ((size_t)(b0 + b) << 8) + tid;
        float v = 0.f, ga = 0.f, wt = 0.0009765625f;   // 2^-10
#pragma unroll
        for (int t = 0; t < T_STEPS; ++t) {
            float I = p[(size_t)t * BATCH * HID];
            v = v + (I - v) * 0.5f;
            if (v >= 1.0f) { ga += wt; v = 0.f; }
            wt += wt;
        }
        gl[(b << 8) + tid] = ga;
    }
    __syncthreads();

    const int wv = tid >> 6;
    const int c  = tid & 63;
    if (c >= NCLS) return;
    float acc[4] = {0.f, 0.f, 0.f, 0.f};
    for (int h4 = 0; h4 < 64; ++h4) {
        float w0 = Wr[((h4 << 2) + 0) * NCLS + c];
        float w1 = Wr[((h4 << 2) + 1) * NCLS + c];
        float w2 = Wr[((h4 << 2) + 2) * NCLS + c];
        float w3 = Wr[((h4 << 2) + 3) * NCLS + c];
#pragma unroll
        for (int j = 0; j < 4; ++j) {
            float4 gg = *(float4*)&gl[(((wv << 2) + j) << 8) + (h4 << 2)];
            acc[j] = fmaf(gg.x, w0, acc[j]);
            acc[j] = fmaf(gg.y, w1, acc[j]);
            acc[j] = fmaf(gg.z, w2, acc[j]);
            acc[j] = fmaf(gg.w, w3, acc[j]);
        }
    }
    float brv = br[c] * 0.9990234375f;
#pragma unroll
    for (int j = 0; j < 4; ++j)
        out[(b0 + (wv << 2) + j) * NCLS + c] = acc[j] + brv;
}

extern "C" void kernel_launch(void* const* d_in, const int* in_sizes, int n_in,
                              void* d_out, int out_size, void* d_ws, size_t ws_size,
                              hipStream_t stream) {
    const float* x  = (const float*)d_in[0];
    const float* W1 = (const float*)d_in[1];
    const float* b1 = (const float*)d_in[2];
    const float* Wr = (const float*)d_in[3];
    const float* br = (const float*)d_in[4];
    float* out = (float*)d_out;

    float*  I_all = (float*) ((char*)d_ws + WS_IALL_OFF);
    ushort* w1hi  = (ushort*)((char*)d_ws + WS_W1HI_OFF);
    ushort* w1md  = (ushort*)((char*)d_ws + WS_W1MD_OFF);
    ushort* w1lo  = (ushort*)((char*)d_ws + WS_W1LO_OFF);

    splitk_k<<<HID, 256, 0, stream>>>(W1, w1hi, w1md, w1lo);
    fused_gemm_k<<<NROWS / 64, 256, 0, stream>>>(w1hi, w1md, w1lo, b1, x, I_all);
    scanout_k<<<BATCH / 16, 256, 0, stream>>>(I_all, Wr, br, out);
}